// Round 2
// baseline (159.770 us; speedup 1.0000x reference)
//
#include <hip/hip_runtime.h>
#include <hip/hip_bf16.h>

// ---------------------------------------------------------------------------
// EuclideanDeconf: out[b,c] = (2*dot(x[b],W[c]) - ||x[b]||^2 - ||W[c]||^2) / D
// R9: B (W matrix) no longer staged in LDS -- its KSPLIT slice (1 MB fp8) is
// L2-resident, and the 32x32x64 B-fragment is directly loadable from global
// (lane l: row l&31, k-bytes (l>>5)*32; lane pairs consume full 64B lines).
// B gets a PD=2 register ring. A keeps R7's PD=3 ring -> LDS double buffer
// (swizzled, conflict-free). LDS traffic halves (was the R8 bottleneck:
// 48 KB/block-step vs 275cy MFMA). LDS now 16 KB. MX-scaled MFMA
// (unit E8M0 scales = exact fp8 math at 2x rate), fp8 partials, split-K=4.
// ---------------------------------------------------------------------------

typedef float f32x4 __attribute__((ext_vector_type(4)));
typedef float f32x2 __attribute__((ext_vector_type(2)));
typedef float f32x16 __attribute__((ext_vector_type(16)));
typedef int i32x4 __attribute__((ext_vector_type(4)));
typedef int i32x8 __attribute__((ext_vector_type(8)));

#define BDIM 4096
#define DDIM 4096
#define CDIM 1024
#define TM 128
#define TN 128
#define BK 64
#define KSPLIT 4
#define NIT ((DDIM / KSPLIT) / BK)   // 16
#define SCALE 32.0f
#define INV_SS (1.0f/1024.0f)
#define PSCALE 0.0625f               // partial pack scale (1/16)

// lgkm-only barrier: ds ops drained; register prefetch loads stay in flight.
#define SYNC_LGKM() asm volatile("s_waitcnt lgkmcnt(0)\n\ts_barrier" ::: "memory")

// One WAVE per row: fp32 row -> fp8(e4m3, x SCALE) row + fp32 sum-of-squares
// (of the UNSCALED values).
__global__ __launch_bounds__(256) void cvt_rowsq(
    const float* __restrict__ x, const float* __restrict__ W,
    unsigned char* __restrict__ xb, unsigned char* __restrict__ wb,
    float* __restrict__ xsq, float* __restrict__ wsq)
{
    const int lane = threadIdx.x & 63;
    const int row = blockIdx.x * 4 + (threadIdx.x >> 6);

    const float* src;
    unsigned char* dst;
    float* sq;
    if (row < BDIM) {
        src = x + (size_t)row * DDIM;
        dst = xb + (size_t)row * DDIM;
        sq = xsq + row;
    } else {
        int r = row - BDIM;
        src = W + (size_t)r * DDIM;
        dst = wb + (size_t)r * DDIM;
        sq = wsq + r;
    }

    const float4* s4 = (const float4*)src;
    unsigned int* d4 = (unsigned int*)dst;
    float a = 0.f;
    #pragma unroll
    for (int s = 0; s < DDIM / 4 / 64; ++s) {
        float4 f = s4[lane + 64 * s];
        a += f.x * f.x + f.y * f.y + f.z * f.z + f.w * f.w;
        unsigned int p = 0;
        p = __builtin_amdgcn_cvt_pk_fp8_f32(f.x * SCALE, f.y * SCALE, p, false);
        p = __builtin_amdgcn_cvt_pk_fp8_f32(f.z * SCALE, f.w * SCALE, p, true);
        d4[lane + 64 * s] = p;
    }
    #pragma unroll
    for (int off = 32; off > 0; off >>= 1) a += __shfl_down(a, off);
    if (lane == 0) *sq = a;
}

// --- GEMM ---
// A LDS layout (verified R8): 16B chunk (row m, chunk c covering k-bytes
// [c*16,c*16+16)) at byte  m*64 + ((c ^ ((m>>1)&3)) * 16). b128 reads and
// writes both bank-conflict-free.
// A fragment: lane l reads row wm+(l&31), chunks c0=(l>>5)*2 and c0+1.
// B fragment: loaded straight from global: two 16B loads per lane at
// row bn+wn+(l&31)(+32), bytes ks + kt*64 + (l>>5)*32 + {0,16}.
struct PrefA { i32x4 a0, a1; };
struct PrefB { i32x4 b00, b01, b10, b11; };

__device__ __forceinline__ i32x8 cat8(i32x4 lo, i32x4 hi) {
    return __builtin_shufflevector(lo, hi, 0, 1, 2, 3, 4, 5, 6, 7);
}

#define MXMFMA(A, Bv, C)                                                  \
    __builtin_amdgcn_mfma_scale_f32_32x32x64_f8f6f4(                      \
        (A), (Bv), (C), 0, 0, 0, 0x7F7F7F7F, 0, 0x7F7F7F7F)

__global__ __launch_bounds__(256, 3) void gemm_eucl(
    const unsigned char* __restrict__ xb,   // [B, D] fp8
    const unsigned char* __restrict__ wb,   // [C, D] fp8
    unsigned int* __restrict__ part)        // [KSPLIT][256 blk][16 frag][256]
{
    __shared__ unsigned char sm[2 * 8192];  // A double buffer only

    const int tid = threadIdx.x;
    const int lane = tid & 63;
    const int wid = tid >> 6;
    const int bm = blockIdx.x * TM;
    const int bn = blockIdx.y * TN;
    const int ks = blockIdx.z * (DDIM / KSPLIT);
    const int wm = (wid >> 1) * 64;
    const int wn = (wid & 1) * 64;

    // A staging: 32-bit voffsets from the scalar base (per-iter advance is a
    // constant imm after full unroll).
    const int r0 = tid >> 2, c = tid & 3;
    const unsigned int oA0 = (unsigned int)((bm + r0) * DDIM + ks + c * 16);
    const unsigned int oA1 = oA0 + 64u * DDIM;

    // A LDS write offset (swizzled b128). Row r0+64 lands at +4096 with the
    // same swizzle.
    const int wo0 = r0 * 64 + ((c ^ ((r0 >> 1) & 3)) * 16);

    // A fragment read offsets: two b128 per tile; tile 2 at +2048.
    const int sswz = (lane >> 1) & 3;
    const int c0 = (lane >> 5) * 2;
    const int m0 = wm + (lane & 31);
    const int aof0 = m0 * 64 + ((c0 ^ sswz) * 16);
    const int aof1 = m0 * 64 + (((c0 + 1) ^ sswz) * 16);

    // B direct-from-global per-lane bases (L2-resident slice).
    const unsigned char* pB0 =
        wb + (size_t)(bn + wn + (lane & 31)) * DDIM + ks + (lane >> 5) * 32;
    const unsigned char* pB1 = pB0 + (size_t)32 * DDIM;

    f32x16 acc[4] = {};   // [A-tile it][B-tile jt]: 0=00 1=01 2=10 3=11

#define ALOAD(S, KT)                                                     \
    do {                                                                 \
        (S).a0 = *(const i32x4*)(xb + oA0 + (KT) * BK);                  \
        (S).a1 = *(const i32x4*)(xb + oA1 + (KT) * BK);                  \
    } while (0)

#define BLOAD(T, KT)                                                     \
    do {                                                                 \
        (T).b00 = *(const i32x4*)(pB0 + (KT) * BK);                      \
        (T).b01 = *(const i32x4*)(pB0 + (KT) * BK + 16);                 \
        (T).b10 = *(const i32x4*)(pB1 + (KT) * BK);                      \
        (T).b11 = *(const i32x4*)(pB1 + (KT) * BK + 16);                 \
    } while (0)

#define AWRITE(buf, S)                                                   \
    do {                                                                 \
        unsigned char* sA = sm + (buf) * 8192;                           \
        *(i32x4*)(sA + wo0) = (S).a0;                                    \
        *(i32x4*)(sA + wo0 + 4096) = (S).a1;                             \
    } while (0)

#define COMPUTE(buf, T)                                                  \
    do {                                                                 \
        const unsigned char* sA = sm + (buf) * 8192;                     \
        i32x8 fb0 = cat8((T).b00, (T).b01);                              \
        i32x8 fb1 = cat8((T).b10, (T).b11);                              \
        i32x8 fa0 = cat8(*(const i32x4*)(sA + aof0),                     \
                         *(const i32x4*)(sA + aof1));                    \
        acc[0] = MXMFMA(fa0, fb0, acc[0]);                               \
        i32x8 fa1 = cat8(*(const i32x4*)(sA + aof0 + 2048),              \
                         *(const i32x4*)(sA + aof1 + 2048));             \
        acc[1] = MXMFMA(fa0, fb1, acc[1]);                               \
        acc[2] = MXMFMA(fa1, fb0, acc[2]);                               \
        acc[3] = MXMFMA(fa1, fb1, acc[3]);                               \
    } while (0)

    PrefA SA[3];   // PD=3: HBM-latency cover for A staging
    PrefB SB[3];   // PD=2 (ring of 3): L2-latency cover for B fragments
    ALOAD(SA[0], 0); BLOAD(SB[0], 0);
    ALOAD(SA[1], 1); BLOAD(SB[1], 1);
    ALOAD(SA[2], 2);
    AWRITE(0, SA[0]);       // compiler waits tile-0 A loads only
    SYNC_LGKM();

    // steady state, fully unrolled (imm-folded offsets)
    #pragma unroll
    for (int k = 0; k < NIT - 1; ++k) {
        if (k < NIT - 3) ALOAD(SA[k % 3], k + 3);       // A tile k+3
        if (k < NIT - 2) BLOAD(SB[(k + 2) % 3], k + 2); // B tile k+2
        COMPUTE(k & 1, SB[k % 3]);                      // tile k
        AWRITE((k + 1) & 1, SA[(k + 1) % 3]);           // A tile k+1
        SYNC_LGKM();
    }
    COMPUTE((NIT - 1) & 1, SB[(NIT - 1) % 3]);          // tile 15

    // fp8 partials, scale 1/16: 1 uint per (tile, reg-group) per thread.
    unsigned int* p = part
        + (((size_t)blockIdx.z * 256 + (blockIdx.x * 8 + blockIdx.y)) * 16) * 256;
    #pragma unroll
    for (int t = 0; t < 4; ++t)
        #pragma unroll
        for (int g = 0; g < 4; ++g) {
            unsigned int pk = 0;
            pk = __builtin_amdgcn_cvt_pk_fp8_f32(
                acc[t][g * 4 + 0] * PSCALE, acc[t][g * 4 + 1] * PSCALE, pk, false);
            pk = __builtin_amdgcn_cvt_pk_fp8_f32(
                acc[t][g * 4 + 2] * PSCALE, acc[t][g * 4 + 3] * PSCALE, pk, true);
            p[(t * 4 + g) * 256 + tid] = pk;
        }
#undef ALOAD
#undef BLOAD
#undef AWRITE
#undef COMPUTE
}

// 512 blocks; block handles 8 frag-groups of one gemm-block. Sums 4 slices
// (fp8 unpack), applies epilogue, scatters to out.
// 32x32 C/D layout: col = lane&31, row = (reg&3) + 8*(reg>>2) + 4*(lane>>5).
// Packed group g holds regs 4g..4g+3 -> row = r + 8g + 4*(lane>>5).
__global__ __launch_bounds__(256) void reduce_out(
    const unsigned int* __restrict__ part, const float* __restrict__ xsq,
    const float* __restrict__ wsq, float* __restrict__ out)
{
    const int bid = blockIdx.x;           // 0..511
    const int bb = bid >> 1;              // gemm block (bx*8 + by)
    const int f0 = (bid & 1) * 8;
    const int t = threadIdx.x;
    const int lane = t & 63;
    const int wid = t >> 6;
    const int bm = (bb >> 3) * TM, bn = (bb & 7) * TN;
    const int wm = (wid >> 1) * 64, wn = (wid & 1) * 64;
    const size_t sl = (size_t)256 * 16 * 256;   // uints per slice
    const float c1 = 2.0f * 16.0f * INV_SS / (float)DDIM;  // 16 = 1/PSCALE
    const float c2 = 1.0f / (float)DDIM;

    #pragma unroll
    for (int f = f0; f < f0 + 8; ++f) {
        size_t o = ((size_t)bb * 16 + f) * 256 + t;
        f32x2 s01 = {0.f, 0.f}, s23 = {0.f, 0.f};
        #pragma unroll
        for (int z = 0; z < KSPLIT; ++z) {
            unsigned int u = part[o + (size_t)z * sl];
            s01 += __builtin_amdgcn_cvt_pk_f32_fp8(u, false);
            s23 += __builtin_amdgcn_cvt_pk_f32_fp8(u, true);
        }
        int t4 = f >> 2, g = f & 3;
        int it = t4 >> 1, jt = t4 & 1;
        int gn = bn + wn + jt * 32 + (lane & 31);
        float wv = wsq[gn];
        int gm0 = bm + wm + it * 32 + (lane >> 5) * 4 + g * 8;
        float sv[4] = {s01.x, s01.y, s23.x, s23.y};
        #pragma unroll
        for (int r = 0; r < 4; ++r) {
            out[(size_t)(gm0 + r) * CDIM + gn] = sv[r] * c1 - (xsq[gm0 + r] + wv) * c2;
        }
    }
}

// --- Fallback: naive fp32 (any ws) ---
__global__ void fallback_kernel(const float* __restrict__ x, const float* __restrict__ W,
                                float* __restrict__ out)
{
    int c = blockIdx.x * blockDim.x + threadIdx.x;
    int b = blockIdx.y;
    if (c >= CDIM) return;
    const float* xr = x + (size_t)b * DDIM;
    const float* wr = W + (size_t)c * DDIM;
    float xs = 0.f, ws = 0.f, cr = 0.f;
    for (int d = 0; d < DDIM; ++d) {
        float xv = xr[d], wv = wr[d];
        xs += xv * xv; ws += wv * wv; cr += xv * wv;
    }
    out[(size_t)b * CDIM + c] = (2.0f * cr - xs - ws) / (float)DDIM;
}

extern "C" void kernel_launch(void* const* d_in, const int* in_sizes, int n_in,
                              void* d_out, int out_size, void* d_ws, size_t ws_size,
                              hipStream_t stream) {
    const float* x = (const float*)d_in[0];   // [B, D] fp32
    const float* W = (const float*)d_in[1];   // [C, D] fp32
    float* out = (float*)d_out;               // [B, C] fp32

    size_t need = (size_t)(BDIM + CDIM) * DDIM                 // fp8 inputs 20 MB
                + (size_t)(BDIM + CDIM) * sizeof(float)        // norms
                + (size_t)KSPLIT * BDIM * CDIM;                // fp8 partials 16 MB
    if (ws_size < need) {
        fallback_kernel<<<dim3(CDIM / 256, BDIM), 256, 0, stream>>>(x, W, out);
        return;
    }

    unsigned char* xb = (unsigned char*)d_ws;              // 16 MB
    unsigned char* wb = xb + (size_t)BDIM * DDIM;          // 4 MB
    float* xsq = (float*)(wb + (size_t)CDIM * DDIM);       // 16 KB
    float* wsq = xsq + BDIM;                               // 4 KB
    unsigned int* part = (unsigned int*)(wsq + CDIM);      // 16 MB

    cvt_rowsq<<<(BDIM + CDIM) / 4, 256, 0, stream>>>(x, W, xb, wb, xsq, wsq);
    gemm_eucl<<<dim3(BDIM / TM, CDIM / TN, KSPLIT), 256, 0, stream>>>(xb, wb, part);
    reduce_out<<<512, 256, 0, stream>>>(part, xsq, wsq, out);
}

// Round 3
// 135.412 us; speedup vs baseline: 1.1799x; 1.1799x over previous
//
#include <hip/hip_runtime.h>
#include <hip/hip_bf16.h>

// ---------------------------------------------------------------------------
// EuclideanDeconf: out[b,c] = (2*dot(x[b],W[c]) - ||x[b]||^2 - ||W[c]||^2) / D
// R10: phased-pipeline GEMM (T3+T4 port). 256x256xBK64 tile, 512 thr (8 waves
// 2Mx4N), global_load_lds direct staging (pre-swizzled per-lane SOURCE addr,
// linear LDS dest, swizzled ds_read_b128 -- rule #21), TWO phases per K-tile:
//   PhB: stage B(t+1)->buf^1 | read B-frags(t) | vmcnt(2) | barrier
//   PhA: stage A(t+1)->buf^1 | read A-frags(t) | 8 MFMA (setprio) | vmcnt(2) | barrier
// Counted vmcnt never drains in-loop; every load flies ~1 full tile (~1100cy).
// MX-scaled MFMA 32x32x64 (unit E8M0 = exact fp8 math at 2x rate), fp8
// partials (1/16), split-K=4. cvt/reduce unchanged in spirit; reduce remapped
// to the new 8-wave 128x64 per-wave geometry.
// ---------------------------------------------------------------------------

typedef float f32x4 __attribute__((ext_vector_type(4)));
typedef float f32x2 __attribute__((ext_vector_type(2)));
typedef float f32x16 __attribute__((ext_vector_type(16)));
typedef int i32x4 __attribute__((ext_vector_type(4)));
typedef int i32x8 __attribute__((ext_vector_type(8)));

#define BDIM 4096
#define DDIM 4096
#define CDIM 1024
#define TM 256
#define TN 256
#define BK 64
#define KSPLIT 4
#define NIT ((DDIM / KSPLIT) / BK)   // 16
#define SCALE 32.0f
#define INV_SS (1.0f/1024.0f)
#define PSCALE 0.0625f               // partial pack scale (1/16)

#define WAITV(N) asm volatile("s_waitcnt vmcnt(" #N ")" ::: "memory")

// One WAVE per row: fp32 row -> fp8(e4m3, x SCALE) row + fp32 sum-of-squares
// (of the UNSCALED values).
__global__ __launch_bounds__(256) void cvt_rowsq(
    const float* __restrict__ x, const float* __restrict__ W,
    unsigned char* __restrict__ xb, unsigned char* __restrict__ wb,
    float* __restrict__ xsq, float* __restrict__ wsq)
{
    const int lane = threadIdx.x & 63;
    const int row = blockIdx.x * 4 + (threadIdx.x >> 6);

    const float* src;
    unsigned char* dst;
    float* sq;
    if (row < BDIM) {
        src = x + (size_t)row * DDIM;
        dst = xb + (size_t)row * DDIM;
        sq = xsq + row;
    } else {
        int r = row - BDIM;
        src = W + (size_t)r * DDIM;
        dst = wb + (size_t)r * DDIM;
        sq = wsq + r;
    }

    const float4* s4 = (const float4*)src;
    unsigned int* d4 = (unsigned int*)dst;
    float a = 0.f;
    #pragma unroll
    for (int s = 0; s < DDIM / 4 / 64; ++s) {
        float4 f = s4[lane + 64 * s];
        a += f.x * f.x + f.y * f.y + f.z * f.z + f.w * f.w;
        unsigned int p = 0;
        p = __builtin_amdgcn_cvt_pk_fp8_f32(f.x * SCALE, f.y * SCALE, p, false);
        p = __builtin_amdgcn_cvt_pk_fp8_f32(f.z * SCALE, f.w * SCALE, p, true);
        d4[lane + 64 * s] = p;
    }
    #pragma unroll
    for (int off = 32; off > 0; off >>= 1) a += __shfl_down(a, off);
    if (lane == 0) *sq = a;
}

// --- GEMM ---
// LDS (64 KiB): buf p at p*32768: A[256][64] fp8 at +0, B[256][64] at +16384.
// Swizzle: 16B chunk (row m, chunk c) stored at slot (m, c ^ ((m>>1)&3)).
// Staging: DMA writes linearly; per-lane SOURCE pre-swizzled (same 64B line
// per 4-lane group -> still fully coalesced). s(m) for staged rows reduces to
// (lane>>3)&3; s(m) for frag rows reduces to ((lane&31)>>1)&3 (i/wr-indep).
// Frag reads: lane l: row base+(l&31), chunks c0=(l>>5)*2 and c0^..^1 ->
// two ds_read_b128; 8-lane groups cover all 32 banks.

__device__ __forceinline__ i32x8 cat8(i32x4 lo, i32x4 hi) {
    return __builtin_shufflevector(lo, hi, 0, 1, 2, 3, 4, 5, 6, 7);
}

#define MXMFMA(A, Bv, C)                                                  \
    __builtin_amdgcn_mfma_scale_f32_32x32x64_f8f6f4(                      \
        (A), (Bv), (C), 0, 0, 0, 0x7F7F7F7F, 0, 0x7F7F7F7F)

#define GLOAD16(gp, lp)                                                   \
    __builtin_amdgcn_global_load_lds(                                     \
        (const __attribute__((address_space(1))) void*)(gp),              \
        (__attribute__((address_space(3))) void*)(lp), 16, 0, 0)

__global__ __launch_bounds__(512, 2) void gemm_eucl(
    const unsigned char* __restrict__ xb,   // [B, D] fp8
    const unsigned char* __restrict__ wb,   // [C, D] fp8
    unsigned int* __restrict__ part)        // [KSPLIT][64 blk][8 tile][4 grp][512]
{
    __shared__ unsigned char sm[2 * 32768];

    const int tid = threadIdx.x;
    const int lane = tid & 63;
    const int w = tid >> 6;                 // wave 0..7
    const int wr = w >> 2;                  // 0..1  (M half: 128 rows)
    const int wc = w & 3;                   // 0..3  (N quarter: 64 rows)
    const int bm = blockIdx.x * TM;
    const int bn = blockIdx.y * TN;
    const int ks = blockIdx.z * (DDIM / KSPLIT);

    // ---- staging: per-lane pre-swizzled global sources (coalesced) ----
    // wave w, issue q: LDS rows [w*32+q*16, +16); lane l -> row +(l>>2),
    // slot cpos=l&3 holds global chunk cpos ^ ((l>>3)&3).
    const int srow = w * 32 + (lane >> 2);
    const int schunk = ((lane & 3) ^ ((lane >> 3) & 3)) * 16;
    const unsigned char* gA0 = xb + (size_t)(bm + srow) * DDIM + ks + schunk;
    const unsigned char* gA1 = gA0 + (size_t)16 * DDIM;
    const unsigned char* gB0 = wb + (size_t)(bn + srow) * DDIM + ks + schunk;
    const unsigned char* gB1 = gB0 + (size_t)16 * DDIM;
    // wave-uniform LDS dests (DMA adds lane*16)
    unsigned char* lA0 = sm + w * 2048;
    unsigned char* lA1 = lA0 + 1024;
    unsigned char* lB0 = sm + 16384 + w * 2048;
    unsigned char* lB1 = lB0 + 1024;

#define STAGE_A(buf, t)                                                   \
    do {                                                                  \
        GLOAD16(gA0 + (t) * BK, lA0 + (buf) * 32768);                     \
        GLOAD16(gA1 + (t) * BK, lA1 + (buf) * 32768);                     \
    } while (0)
#define STAGE_B(buf, t)                                                   \
    do {                                                                  \
        GLOAD16(gB0 + (t) * BK, lB0 + (buf) * 32768);                     \
        GLOAD16(gB1 + (t) * BK, lB1 + (buf) * 32768);                     \
    } while (0)

    // ---- fragment read bases (swizzled) ----
    const int s_rd = ((lane & 31) >> 1) & 3;
    const int c0s = ((lane >> 5) * 2) ^ s_rd;
    const unsigned char* aR0 = sm + (wr * 128 + (lane & 31)) * 64 + c0s * 16;
    const unsigned char* aR1 = sm + (wr * 128 + (lane & 31)) * 64 + (c0s ^ 1) * 16;
    const unsigned char* bR0 = sm + 16384 + (wc * 64 + (lane & 31)) * 64 + c0s * 16;
    const unsigned char* bR1 = sm + 16384 + (wc * 64 + (lane & 31)) * 64 + (c0s ^ 1) * 16;

    f32x16 acc[8] = {};   // [i 0..3][j 0..1] -> acc[i*2+j]

    // ---- prologue: tile 0 -> buf0, drain, barrier ----
    STAGE_B(0, 0);
    STAGE_A(0, 0);
    WAITV(0);
    __builtin_amdgcn_s_barrier();

    i32x8 fb0, fb1;

    #pragma unroll
    for (int t = 0; t < NIT; ++t) {
        const int p = t & 1;
        const int po = p * 32768;
        // ---------- Phase B ----------
        if (t + 1 < NIT) STAGE_B(p ^ 1, t + 1);
        fb0 = cat8(*(const i32x4*)(bR0 + po), *(const i32x4*)(bR1 + po));
        fb1 = cat8(*(const i32x4*)(bR0 + po + 2048), *(const i32x4*)(bR1 + po + 2048));
        if (t + 1 < NIT) WAITV(2);   // A(t) collectively landed; B(t+1) flying
        else             WAITV(0);
        __builtin_amdgcn_s_barrier();
        // ---------- Phase A ----------
        if (t + 1 < NIT) STAGE_A(p ^ 1, t + 1);
        {
            i32x8 fa0 = cat8(*(const i32x4*)(aR0 + po), *(const i32x4*)(aR1 + po));
            i32x8 fa1 = cat8(*(const i32x4*)(aR0 + po + 2048), *(const i32x4*)(aR1 + po + 2048));
            i32x8 fa2 = cat8(*(const i32x4*)(aR0 + po + 4096), *(const i32x4*)(aR1 + po + 4096));
            i32x8 fa3 = cat8(*(const i32x4*)(aR0 + po + 6144), *(const i32x4*)(aR1 + po + 6144));
            __builtin_amdgcn_s_setprio(1);
            acc[0] = MXMFMA(fa0, fb0, acc[0]);
            acc[1] = MXMFMA(fa0, fb1, acc[1]);
            acc[2] = MXMFMA(fa1, fb0, acc[2]);
            acc[3] = MXMFMA(fa1, fb1, acc[3]);
            acc[4] = MXMFMA(fa2, fb0, acc[4]);
            acc[5] = MXMFMA(fa2, fb1, acc[5]);
            acc[6] = MXMFMA(fa3, fb0, acc[6]);
            acc[7] = MXMFMA(fa3, fb1, acc[7]);
            __builtin_amdgcn_s_setprio(0);
        }
        if (t + 1 < NIT) {
            WAITV(2);                // B(t+1) landed; A(t+1) flying
            __builtin_amdgcn_s_barrier();
        }
    }

    // ---- fp8 partials, scale 1/16 ----
    const int bb = blockIdx.x * 4 + blockIdx.y;          // 0..63
    unsigned int* p = part + ((size_t)blockIdx.z * 64 + bb) * (32 * 512);
    #pragma unroll
    for (int f = 0; f < 8; ++f)
        #pragma unroll
        for (int g = 0; g < 4; ++g) {
            unsigned int pk = 0;
            pk = __builtin_amdgcn_cvt_pk_fp8_f32(
                acc[f][g * 4 + 0] * PSCALE, acc[f][g * 4 + 1] * PSCALE, pk, false);
            pk = __builtin_amdgcn_cvt_pk_fp8_f32(
                acc[f][g * 4 + 2] * PSCALE, acc[f][g * 4 + 3] * PSCALE, pk, true);
            p[(f * 4 + g) * 512 + tid] = pk;
        }
#undef STAGE_A
#undef STAGE_B
}

// 512 blocks x 256 thr; reduce block = one gemm-wave's 128x64 region.
// 32x32 C/D layout: col = lane&31, row = (reg&3) + 8*(reg>>2) + 4*(lane>>5);
// packed grp g holds regs 4g..4g+3 -> row = r + 8g + 4*(lane>>5).
__global__ __launch_bounds__(256) void reduce_out(
    const unsigned int* __restrict__ part, const float* __restrict__ xsq,
    const float* __restrict__ wsq, float* __restrict__ out)
{
    const int bid = blockIdx.x;           // 0..511
    const int bb = bid >> 3;              // gemm block 0..63 (bx*4 + by)
    const int w = bid & 7;                // gemm wave
    const int wr = w >> 2, wc = w & 3;
    const int t = threadIdx.x;
    const int lane = t & 63;
    const int g = t >> 6;                 // packed group 0..3
    const int bm = (bb >> 2) * TM, bn = (bb & 3) * TN;
    const size_t sl = (size_t)64 * 32 * 512;     // uints per z-slice
    const float c1 = 2.0f * 16.0f * INV_SS / (float)DDIM;  // 16 = 1/PSCALE
    const float c2 = 1.0f / (float)DDIM;

    #pragma unroll
    for (int f = 0; f < 8; ++f) {
        size_t o = ((size_t)bb * 32 + f * 4 + g) * 512 + w * 64 + lane;
        f32x2 s01 = {0.f, 0.f}, s23 = {0.f, 0.f};
        #pragma unroll
        for (int z = 0; z < KSPLIT; ++z) {
            unsigned int u = part[o + (size_t)z * sl];
            s01 += __builtin_amdgcn_cvt_pk_f32_fp8(u, false);
            s23 += __builtin_amdgcn_cvt_pk_f32_fp8(u, true);
        }
        int i = f >> 1, j = f & 1;
        int gn = bn + wc * 64 + j * 32 + (lane & 31);
        float wv = wsq[gn];
        int gm0 = bm + wr * 128 + i * 32 + 8 * g + 4 * (lane >> 5);
        float sv[4] = {s01.x, s01.y, s23.x, s23.y};
        #pragma unroll
        for (int r = 0; r < 4; ++r) {
            out[(size_t)(gm0 + r) * CDIM + gn] = sv[r] * c1 - (xsq[gm0 + r] + wv) * c2;
        }
    }
}

// --- Fallback: naive fp32 (any ws) ---
__global__ void fallback_kernel(const float* __restrict__ x, const float* __restrict__ W,
                                float* __restrict__ out)
{
    int c = blockIdx.x * blockDim.x + threadIdx.x;
    int b = blockIdx.y;
    if (c >= CDIM) return;
    const float* xr = x + (size_t)b * DDIM;
    const float* wr = W + (size_t)c * DDIM;
    float xs = 0.f, ws = 0.f, cr = 0.f;
    for (int d = 0; d < DDIM; ++d) {
        float xv = xr[d], wv = wr[d];
        xs += xv * xv; ws += wv * wv; cr += xv * wv;
    }
    out[(size_t)b * CDIM + c] = (2.0f * cr - xs - ws) / (float)DDIM;
}

extern "C" void kernel_launch(void* const* d_in, const int* in_sizes, int n_in,
                              void* d_out, int out_size, void* d_ws, size_t ws_size,
                              hipStream_t stream) {
    const float* x = (const float*)d_in[0];   // [B, D] fp32
    const float* W = (const float*)d_in[1];   // [C, D] fp32
    float* out = (float*)d_out;               // [B, C] fp32

    size_t need = (size_t)(BDIM + CDIM) * DDIM                 // fp8 inputs 20 MB
                + (size_t)(BDIM + CDIM) * sizeof(float)        // norms
                + (size_t)KSPLIT * BDIM * CDIM;                // fp8 partials 16 MB
    if (ws_size < need) {
        fallback_kernel<<<dim3(CDIM / 256, BDIM), 256, 0, stream>>>(x, W, out);
        return;
    }

    unsigned char* xb = (unsigned char*)d_ws;              // 16 MB
    unsigned char* wb = xb + (size_t)BDIM * DDIM;          // 4 MB
    float* xsq = (float*)(wb + (size_t)CDIM * DDIM);       // 16 KB
    float* wsq = xsq + BDIM;                               // 4 KB
    unsigned int* part = (unsigned int*)(wsq + CDIM);      // 16 MB

    cvt_rowsq<<<(BDIM + CDIM) / 4, 256, 0, stream>>>(x, W, xb, wb, xsq, wsq);
    gemm_eucl<<<dim3(BDIM / TM, CDIM / TN, KSPLIT), 512, 0, stream>>>(xb, wb, part);
    reduce_out<<<512, 256, 0, stream>>>(part, xsq, wsq, out);
}